// Round 3
// baseline (298.362 us; speedup 1.0000x reference)
//
#include <hip/hip_runtime.h>
#include <math.h>

#define L2E 1.4426950408889634f
#define HSTR 136   // h LDS row stride (bf16): 272B -> dword stride 68 ≡ 4 (mod 32), clean per-quad bank spread

typedef __bf16 bf16x8 __attribute__((ext_vector_type(8)));
typedef float  f32x4  __attribute__((ext_vector_type(4)));

__device__ __forceinline__ float sig2(float y) {  // sigmoid(x) with y = x*log2e
    return __builtin_amdgcn_rcpf(1.0f + __builtin_amdgcn_exp2f(-y));
}

// ---------------- prep: stats LUT + zero accumulators + rank-1 input vectors ----------------
__global__ void prep_kernel(const float* __restrict__ numbers,
                            const float* __restrict__ w_num,
                            const float* __restrict__ b_num,
                            const float* __restrict__ W_ih,
                            const float* __restrict__ b_ih,
                            const float* __restrict__ b_hh,
                            float* __restrict__ ws_base) {
    float* fc_hs    = ws_base;        // 256 floats (fc_sum + hs_bar)
    float* mean_lut = ws_base + 256;  // 100
    float* inv_lut  = ws_base + 356;  // 100
    float* Avec     = ws_base + 456;  // 512
    float* Bvec     = ws_base + 968;  // 512

    if (blockIdx.x == 64) {
        __shared__ float sx[100];
        int tid = threadIdx.x;
        if (tid < 256) fc_hs[tid] = 0.0f;
        if (tid < 100) sx[tid] = numbers[tid];
        __syncthreads();
        if (tid < 100) {
            float s = 0.f, ss = 0.f;
            for (int j = 0; j <= tid; ++j) { float v = sx[j]; s += v; ss += v * v; }
            float cap  = (float)(tid + 1);
            float mean = s / cap;
            float var  = ss / cap - mean * mean;
            if (var < 0.f) var = 0.f;
            float sd = sqrtf(var);
            float inv = (cap > 3.0f && sd > 1e-8f) ? (1.0f / sd) : 1.0f;
            mean_lut[tid] = mean;
            inv_lut[tid]  = inv;
        }
        return;
    }
    int j    = blockIdx.x * 8 + (threadIdx.x >> 6);   // 0..511
    int lane = threadIdx.x & 63;
    const float* row = W_ih + j * 256 + 128;
    float r1 = row[lane], r2 = row[lane + 64];
    float a = r1 * w_num[lane] + r2 * w_num[lane + 64];
    float b = r1 * b_num[lane] + r2 * b_num[lane + 64];
    #pragma unroll
    for (int off = 32; off >= 1; off >>= 1) {
        a += __shfl_xor(a, off);
        b += __shfl_xor(b, off);
    }
    if (lane == 0) {
        float s = (j >= 256 && j < 384) ? (2.0f * L2E) : L2E;  // g gate gets 2*log2e
        Avec[j] = a * s;
        Bvec[j] = (b + b_ih[j] + b_hh[j]) * s;
    }
}

// ---------------- main: 128-step LSTM, 16 rows/block, 16 waves, redundant-pair row split ----
// Waves w and w+8 compute the SAME 16-col x 4-gate MFMA tile (m0=(w&7)*16);
// gate math is split by accumulator register index (par=0 -> rows quad*4+{0,1},
// par=1 -> rows quad*4+{2,3}). One barrier per step, no cross-wave data exchange.
__global__ __launch_bounds__(1024, 4) void lstm_kernel(
        const float* __restrict__ numbers, const float* __restrict__ W_hh,
        const float* __restrict__ W_fh,    const float* __restrict__ b_fh,
        const float* __restrict__ mean_lut, const float* __restrict__ inv_lut,
        const float* __restrict__ Avec,     const float* __restrict__ Bvec,
        float* __restrict__ fc_sum, float* __restrict__ hs_bar) {
    __shared__ unsigned short hbuf[2][16 * HSTR];   // h state, bf16, [row][col]
    __shared__ float xls[128 * 16];                 // normalized x, [t][row]

    const int tid  = threadIdx.x;
    const int lane = tid & 63;
    const int wave = tid >> 6;        // 0..15
    const int par  = wave >> 3;       // 0: regs {0,1}, 1: regs {2,3}
    const int quad = lane >> 4;
    const int lcol = lane & 15;
    const int m0   = (wave & 7) * 16;
    const int r0   = blockIdx.x * 16;

    for (int i = tid; i < 16 * 128; i += 1024) {
        int row = i >> 7;
        int t   = i & 127;
        int flat = (r0 + row) * 128 + t;
        int ii = (flat < 100) ? flat : 99;
        float v = numbers[flat];
        xls[t * 16 + row] = (v - mean_lut[ii]) * inv_lut[ii];
    }
    for (int i = tid; i < 16 * HSTR; i += 1024) hbuf[0][i] = 0;

    // persistent W_hh B-fragments, all 4 gates (i=0,f=1,g=2,o=3), log2e-folded
    bf16x8 bf[4][4];
    #pragma unroll
    for (int g = 0; g < 4; ++g) {
        float sc = (g == 2) ? (2.0f * L2E) : L2E;
        #pragma unroll
        for (int kk = 0; kk < 4; ++kk) {
            const float* p = W_hh + (g * 128 + m0 + lcol) * 128 + kk * 32 + quad * 8;
            f32x4 w0 = *(const f32x4*)p;
            f32x4 w1 = *(const f32x4*)(p + 4);
            bf16x8 bt;
            #pragma unroll
            for (int q = 0; q < 4; ++q) {
                bt[q]     = (__bf16)(w0[q] * sc);
                bt[q + 4] = (__bf16)(w1[q] * sc);
            }
            bf[g][kk] = bt;
        }
    }
    float ag[4], bg[4];
    #pragma unroll
    for (int g = 0; g < 4; ++g) {
        ag[g] = Avec[g * 128 + m0 + lcol];
        bg[g] = Bvec[g * 128 + m0 + lcol];
    }

    float c0 = 0.f, c1 = 0.f, h0 = 0.f, h1 = 0.f;
    __syncthreads();

// tail for one row register R: p = sig(i)tanh(g); c' = sig(f)c + p; h = sig(o)tanh(c')
#define ROW_TAIL(R, cS, hS)                                                          \
    {                                                                                \
        float e1 = __builtin_amdgcn_exp2f(-aI[R]);                                   \
        float e2 = __builtin_amdgcn_exp2f(aG[R]);                                    \
        float pp = (e2 - 1.0f) * __builtin_amdgcn_rcpf((1.0f + e1) * (e2 + 1.0f));   \
        float sf = sig2(aF[R]);                                                      \
        float cn = sf * cS + pp;                                                     \
        cS = cn;                                                                     \
        float e3 = __builtin_amdgcn_exp2f(cn * (2.0f * L2E));                        \
        float e4 = __builtin_amdgcn_exp2f(-aO[R]);                                   \
        hS = (e3 - 1.0f) * __builtin_amdgcn_rcpf((1.0f + e4) * (e3 + 1.0f));         \
        hout[(quad * 4 + (R)) * HSTR + m0 + lcol] =                                  \
            __builtin_bit_cast(unsigned short, (__bf16)hS);                          \
    }

    for (int t = 0; t < 128; ++t) {
        const unsigned short* hin  = hbuf[t & 1];
        unsigned short*       hout = hbuf[(t + 1) & 1];
        bf16x8 af[4];
        #pragma unroll
        for (int kk = 0; kk < 4; ++kk)
            af[kk] = *(const bf16x8*)(const void*)(hin + lcol * HSTR + kk * 32 + quad * 8);
        f32x4 xq = *(const f32x4*)(const void*)(xls + t * 16 + quad * 4);

        f32x4 aI, aG, aF, aO;
        #pragma unroll
        for (int r = 0; r < 4; ++r) {
            aI[r] = xq[r] * ag[0] + bg[0];
            aG[r] = xq[r] * ag[2] + bg[2];
            aF[r] = xq[r] * ag[1] + bg[1];
            aO[r] = xq[r] * ag[3] + bg[3];
        }
        #pragma unroll
        for (int kk = 0; kk < 4; ++kk) {
            aI = __builtin_amdgcn_mfma_f32_16x16x32_bf16(af[kk], bf[0][kk], aI, 0, 0, 0);
            aG = __builtin_amdgcn_mfma_f32_16x16x32_bf16(af[kk], bf[2][kk], aG, 0, 0, 0);
        }
        #pragma unroll
        for (int kk = 0; kk < 4; ++kk) {
            aF = __builtin_amdgcn_mfma_f32_16x16x32_bf16(af[kk], bf[1][kk], aF, 0, 0, 0);
            aO = __builtin_amdgcn_mfma_f32_16x16x32_bf16(af[kk], bf[3][kk], aO, 0, 0, 0);
        }
        if (par == 0) {
            ROW_TAIL(0, c0, h0)
            ROW_TAIL(1, c1, h1)
        } else {
            ROW_TAIL(2, c0, h0)
            ROW_TAIL(3, c1, h1)
        }
        __syncthreads();
    }
#undef ROW_TAIL

    // hs_bar partial: this wave's 2 regs x 4 quads = 8 rows; pair wave covers the rest
    float v = h0 + h1;
    v += __shfl_xor(v, 16);
    v += __shfl_xor(v, 32);
    if (lane < 16) atomicAdd(&hs_bar[m0 + lane], v);

    // f_g = sig(h @ W_fh^T + b_fh); fc partial (redundant MFMA in the pair, rows split)
    f32x4 facc;
    {
        float bb = b_fh[m0 + lcol] * L2E;
        #pragma unroll
        for (int r = 0; r < 4; ++r) facc[r] = bb;
    }
    #pragma unroll
    for (int kk = 0; kk < 4; ++kk) {
        bf16x8 afr = *(const bf16x8*)(const void*)(hbuf[0] + lcol * HSTR + kk * 32 + quad * 8);
        const float* p = W_fh + (m0 + lcol) * 128 + kk * 32 + quad * 8;
        f32x4 w0 = *(const f32x4*)p;
        f32x4 w1 = *(const f32x4*)(p + 4);
        bf16x8 wt;
        #pragma unroll
        for (int q = 0; q < 4; ++q) {
            wt[q]     = (__bf16)(w0[q] * L2E);
            wt[q + 4] = (__bf16)(w1[q] * L2E);
        }
        facc = __builtin_amdgcn_mfma_f32_16x16x32_bf16(afr, wt, facc, 0, 0, 0);
    }
    float fcv = (par == 0) ? (sig2(facc[0]) * c0 + sig2(facc[1]) * c1)
                           : (sig2(facc[2]) * c0 + sig2(facc[3]) * c1);
    fcv += __shfl_xor(fcv, 16);
    fcv += __shfl_xor(fcv, 32);
    if (lane < 16) atomicAdd(&fc_sum[m0 + lane], fcv);
}

// ---------------- epilogue: root Tree-LSTM cell + output projection ----------------
__global__ void finalize_kernel(const float* __restrict__ fc_sum,
                                const float* __restrict__ hs_bar,
                                const float* __restrict__ W_iouh,
                                const float* __restrict__ b_iouh,
                                const float* __restrict__ W_lout,
                                const float* __restrict__ b_lout,
                                float* __restrict__ out) {
    __shared__ float hsb[128], iou[384], hfin[128];
    int tid = threadIdx.x;
    if (tid < 128) hsb[tid] = hs_bar[tid];
    __syncthreads();
    if (tid < 384) {
        float s = b_iouh[tid];
        const f32x4* row = (const f32x4*)(W_iouh + tid * 128);
        #pragma unroll 8
        for (int m = 0; m < 32; ++m) {
            f32x4 w = row[m];
            s += w[0] * hsb[4*m] + w[1] * hsb[4*m+1] + w[2] * hsb[4*m+2] + w[3] * hsb[4*m+3];
        }
        iou[tid] = s;
    }
    __syncthreads();
    if (tid < 128) {
        float i = iou[tid], o = iou[128 + tid], u = iou[256 + tid];
        float cf = sig2(i * L2E) * (2.0f * sig2(u * 2.0f * L2E) - 1.0f) + fc_sum[tid];
        out[tid] = cf;
        hfin[tid] = sig2(o * L2E) * (2.0f * sig2(cf * 2.0f * L2E) - 1.0f);
    }
    __syncthreads();
    if (tid < 128) {
        float s = b_lout[tid];
        const f32x4* row = (const f32x4*)(W_lout + tid * 128);
        #pragma unroll 8
        for (int m = 0; m < 32; ++m) {
            f32x4 w = row[m];
            s += w[0] * hfin[4*m] + w[1] * hfin[4*m+1] + w[2] * hfin[4*m+2] + w[3] * hfin[4*m+3];
        }
        out[128 + tid] = s;
    }
}

extern "C" void kernel_launch(void* const* d_in, const int* in_sizes, int n_in,
                              void* d_out, int out_size, void* d_ws, size_t ws_size,
                              hipStream_t stream) {
    const float* numbers = (const float*)d_in[0];
    const float* w_num   = (const float*)d_in[1];
    const float* b_num   = (const float*)d_in[2];
    const float* W_ih    = (const float*)d_in[3];
    const float* W_hh    = (const float*)d_in[4];
    const float* b_ih    = (const float*)d_in[5];
    const float* b_hh    = (const float*)d_in[6];
    const float* W_fh    = (const float*)d_in[7];
    const float* b_fh    = (const float*)d_in[8];
    const float* W_iouh  = (const float*)d_in[9];
    const float* b_iouh  = (const float*)d_in[10];
    const float* W_lout  = (const float*)d_in[11];
    const float* b_lout  = (const float*)d_in[12];
    float* out = (float*)d_out;

    float* ws       = (float*)d_ws;
    float* fc_sum   = ws;         // 128
    float* hs_bar   = ws + 128;   // 128
    float* mean_lut = ws + 256;   // 100
    float* inv_lut  = ws + 356;   // 100
    float* Avec     = ws + 456;   // 512
    float* Bvec     = ws + 968;   // 512

    prep_kernel<<<65, 512, 0, stream>>>(numbers, w_num, b_num, W_ih, b_ih, b_hh, ws);
    lstm_kernel<<<256, 1024, 0, stream>>>(numbers, W_hh, W_fh, b_fh,
                                          mean_lut, inv_lut, Avec, Bvec, fc_sum, hs_bar);
    finalize_kernel<<<1, 384, 0, stream>>>(fc_sum, hs_bar, W_iouh, b_iouh, W_lout, b_lout, out);
}

// Round 4
// 264.336 us; speedup vs baseline: 1.1287x; 1.1287x over previous
//
#include <hip/hip_runtime.h>
#include <math.h>

#define L2E 1.4426950408889634f
#define HSTR 136   // h LDS row stride (bf16): 272B

typedef __bf16 bf16x8 __attribute__((ext_vector_type(8)));
typedef float  f32x4  __attribute__((ext_vector_type(4)));

__device__ __forceinline__ float sig2(float y) {  // sigmoid(x), y = x*log2e
    return __builtin_amdgcn_rcpf(1.0f + __builtin_amdgcn_exp2f(-y));
}

// ============ fused: prep (stats + rank-1) + 128-step LSTM + per-block partials ============
// 256 blocks x 1024 thr. Waves w and w+8 compute the SAME 16-col x 4-gate MFMA tile
// (redundant pair); tail split by acc register index (par=0 -> regs 0,1; par=1 -> regs 2,3).
// One barrier per step. Register budget: bf 64 + acc 16 + rolled af 8 + ag/bg 8 + misc ~= 112.
__global__ __launch_bounds__(1024, 4) void lstm_kernel(
        const float* __restrict__ numbers,
        const float* __restrict__ w_num, const float* __restrict__ b_num,
        const float* __restrict__ W_ih,  const float* __restrict__ W_hh,
        const float* __restrict__ b_ih,  const float* __restrict__ b_hh,
        const float* __restrict__ W_fh,  const float* __restrict__ b_fh,
        float* __restrict__ partials) {
    __shared__ unsigned short hbuf[2][16 * HSTR];
    __shared__ float xls[128 * 16];
    __shared__ float abw[8 * 128];     // per col-tile: A in [0..63], B in [64..127]
    __shared__ float wnum_s[128], bnum_s[128];
    __shared__ float sx[100], lutm[100], luti[100];
    __shared__ float accs[256];        // hsum 0..127, fsum 128..255
    __shared__ float s_m99, s_i99;

    const int tid  = threadIdx.x;
    const int lane = tid & 63;
    const int wave = tid >> 6;        // 0..15
    const int par  = wave >> 3;       // acc-register split
    const int quad = lane >> 4;
    const int lcol = lane & 15;
    const int m0   = (wave & 7) * 16;
    const int r0   = blockIdx.x * 16;

    // ---- prologue stage 1: stage small vectors, zero state ----
    if (tid < 128) { wnum_s[tid] = w_num[tid]; bnum_s[tid] = b_num[tid]; }
    if (tid < 100) sx[tid] = numbers[tid];
    if (tid < 256) accs[tid] = 0.0f;
    for (int i = tid; i < 16 * HSTR; i += 1024) hbuf[0][i] = 0;
    __syncthreads();

    // stats over first 100 numbers (every block; cheap)
    if (wave == 0) {
        float v1 = sx[lane];
        float v2 = (lane < 36) ? sx[64 + lane] : 0.0f;
        float s = v1 + v2, ss = v1 * v1 + v2 * v2;
        #pragma unroll
        for (int off = 32; off >= 1; off >>= 1) {
            s += __shfl_xor(s, off);
            ss += __shfl_xor(ss, off);
        }
        if (lane == 0) {
            float mean = s * 0.01f;
            float var  = ss * 0.01f - mean * mean;
            if (var < 0.f) var = 0.f;
            float sd = sqrtf(var);
            s_m99 = mean;
            s_i99 = (sd > 1e-8f) ? (1.0f / sd) : 1.0f;
        }
    }
    // per-k LUT for flat<100 (only block 0 ever uses it)
    if (blockIdx.x == 0 && tid < 100) {
        float s = 0.f, ss = 0.f;
        for (int j = 0; j <= tid; ++j) { float v = sx[j]; s += v; ss += v * v; }
        float cap  = (float)(tid + 1);
        float mean = s / cap;
        float var  = ss / cap - mean * mean;
        if (var < 0.f) var = 0.f;
        float sd = sqrtf(var);
        lutm[tid] = mean;
        luti[tid] = (cap > 3.0f && sd > 1e-8f) ? (1.0f / sd) : 1.0f;
    }
    // rank-1 vectors: lane computes A[j],B[j], j = g*128 + m0 + lcol, g = lane>>4.
    // Pair waves write identical values to the same slots (benign).
    {
        int g = lane >> 4;
        int j = g * 128 + m0 + lcol;
        const float* row = W_ih + j * 256 + 128;
        float a = 0.f, b = 0.f;
        #pragma unroll 4
        for (int m = 0; m < 128; m += 4) {
            f32x4 w  = *(const f32x4*)(row + m);
            f32x4 wn = *(const f32x4*)(wnum_s + m);
            f32x4 bn = *(const f32x4*)(bnum_s + m);
            a += w[0]*wn[0] + w[1]*wn[1] + w[2]*wn[2] + w[3]*wn[3];
            b += w[0]*bn[0] + w[1]*bn[1] + w[2]*bn[2] + w[3]*bn[3];
        }
        float sc = (g == 2) ? (2.0f * L2E) : L2E;   // g gate folded 2*log2e
        abw[(wave & 7) * 128 + lane]      = a * sc;
        abw[(wave & 7) * 128 + 64 + lane] = (b + b_ih[j] + b_hh[j]) * sc;
    }
    __syncthreads();

    // ---- normalize x into xls [t][row] ----
    for (int i = tid; i < 2048; i += 1024) {
        int row = i >> 7, t = i & 127;
        int flat = (r0 + row) * 128 + t;
        float v = numbers[flat];
        float mn, iv;
        if (flat < 100) { mn = lutm[flat]; iv = luti[flat]; }
        else            { mn = s_m99;     iv = s_i99; }
        xls[t * 16 + row] = (v - mn) * iv;
    }

    // ---- persistent W_hh B-fragments (bf16, log2e-folded), 64 VGPRs ----
    bf16x8 bfr[4][4];
    #pragma unroll
    for (int g = 0; g < 4; ++g) {
        float sc = (g == 2) ? (2.0f * L2E) : L2E;
        #pragma unroll
        for (int kk = 0; kk < 4; ++kk) {
            const float* p = W_hh + (g * 128 + m0 + lcol) * 128 + kk * 32 + quad * 8;
            f32x4 w0 = *(const f32x4*)p;
            f32x4 w1 = *(const f32x4*)(p + 4);
            bf16x8 bt;
            #pragma unroll
            for (int q = 0; q < 4; ++q) {
                bt[q]     = (__bf16)(w0[q] * sc);
                bt[q + 4] = (__bf16)(w1[q] * sc);
            }
            bfr[g][kk] = bt;
        }
    }
    float ag[4], bg[4];
    #pragma unroll
    for (int g = 0; g < 4; ++g) {
        ag[g] = abw[(wave & 7) * 128 + g * 16 + lcol];
        bg[g] = abw[(wave & 7) * 128 + 64 + g * 16 + lcol];
    }
    float c0 = 0.f, c1 = 0.f, h0 = 0.f, h1 = 0.f;
    __syncthreads();

#define ROW_TAIL(R, cS, hS)                                                          \
    {                                                                                \
        float e1 = __builtin_amdgcn_exp2f(-aI[R]);                                   \
        float e2 = __builtin_amdgcn_exp2f(aG[R]);                                    \
        float pp = (e2 - 1.0f) * __builtin_amdgcn_rcpf((1.0f + e1) * (e2 + 1.0f));   \
        float sf = sig2(aF[R]);                                                      \
        float cn = sf * cS + pp;                                                     \
        cS = cn;                                                                     \
        float e3 = __builtin_amdgcn_exp2f(cn * (2.0f * L2E));                        \
        float e4 = __builtin_amdgcn_exp2f(-aO[R]);                                   \
        hS = (e3 - 1.0f) * __builtin_amdgcn_rcpf((1.0f + e4) * (e3 + 1.0f));         \
        hout[(quad * 4 + (R)) * HSTR + m0 + lcol] =                                  \
            __builtin_bit_cast(unsigned short, (__bf16)hS);                          \
    }

    for (int t = 0; t < 128; ++t) {
        const unsigned short* hin  = hbuf[t & 1];
        unsigned short*       hout = hbuf[(t + 1) & 1];
        f32x4 xq = *(const f32x4*)(const void*)(xls + t * 16 + quad * 4);
        f32x4 aI, aG, aF, aO;
        #pragma unroll
        for (int r = 0; r < 4; ++r) {
            aI[r] = xq[r] * ag[0] + bg[0];
            aF[r] = xq[r] * ag[1] + bg[1];
            aG[r] = xq[r] * ag[2] + bg[2];
            aO[r] = xq[r] * ag[3] + bg[3];
        }
        #pragma unroll
        for (int kk = 0; kk < 4; ++kk) {   // af rolled: <=2 frags live
            bf16x8 af = *(const bf16x8*)(const void*)(hin + lcol * HSTR + kk * 32 + quad * 8);
            aI = __builtin_amdgcn_mfma_f32_16x16x32_bf16(af, bfr[0][kk], aI, 0, 0, 0);
            aF = __builtin_amdgcn_mfma_f32_16x16x32_bf16(af, bfr[1][kk], aF, 0, 0, 0);
            aG = __builtin_amdgcn_mfma_f32_16x16x32_bf16(af, bfr[2][kk], aG, 0, 0, 0);
            aO = __builtin_amdgcn_mfma_f32_16x16x32_bf16(af, bfr[3][kk], aO, 0, 0, 0);
        }
        if (par == 0) {
            ROW_TAIL(0, c0, h0)
            ROW_TAIL(1, c1, h1)
        } else {
            ROW_TAIL(2, c0, h0)
            ROW_TAIL(3, c1, h1)
        }
        __syncthreads();
    }
#undef ROW_TAIL

    // ---- block-local reductions into LDS (no global atomics) ----
    {
        float v = h0 + h1;
        v += __shfl_xor(v, 16);
        v += __shfl_xor(v, 32);
        if (lane < 16) atomicAdd(&accs[m0 + lane], v);
    }
    {
        f32x4 facc;
        float bb = b_fh[m0 + lcol] * L2E;
        #pragma unroll
        for (int r = 0; r < 4; ++r) facc[r] = bb;
        #pragma unroll
        for (int kk = 0; kk < 4; ++kk) {
            bf16x8 afr = *(const bf16x8*)(const void*)(hbuf[0] + lcol * HSTR + kk * 32 + quad * 8);
            const float* p = W_fh + (m0 + lcol) * 128 + kk * 32 + quad * 8;
            f32x4 w0 = *(const f32x4*)p;
            f32x4 w1 = *(const f32x4*)(p + 4);
            bf16x8 wt;
            #pragma unroll
            for (int q = 0; q < 4; ++q) {
                wt[q]     = (__bf16)(w0[q] * L2E);
                wt[q + 4] = (__bf16)(w1[q] * L2E);
            }
            facc = __builtin_amdgcn_mfma_f32_16x16x32_bf16(afr, wt, facc, 0, 0, 0);
        }
        float fcv = (par == 0) ? (sig2(facc[0]) * c0 + sig2(facc[1]) * c1)
                               : (sig2(facc[2]) * c0 + sig2(facc[3]) * c1);
        fcv += __shfl_xor(fcv, 16);
        fcv += __shfl_xor(fcv, 32);
        if (lane < 16) atomicAdd(&accs[128 + m0 + lane], fcv);
    }
    __syncthreads();
    if (tid < 256) partials[blockIdx.x * 256 + tid] = accs[tid];
}

// ============ finalize: reduce partials + root Tree-LSTM cell + projection ============
__global__ void finalize_kernel(const float* __restrict__ partials,
                                const float* __restrict__ W_iouh,
                                const float* __restrict__ b_iouh,
                                const float* __restrict__ W_lout,
                                const float* __restrict__ b_lout,
                                float* __restrict__ out) {
    __shared__ float hsb[128], fcs[128], iou[384], hfin[128];
    int tid = threadIdx.x;
    if (tid < 256) {
        int m = tid & 127, sel = tid >> 7;
        const float* p = partials + sel * 128 + m;
        float s0 = 0.f, s1 = 0.f, s2 = 0.f, s3 = 0.f;
        #pragma unroll 4
        for (int b = 0; b < 256; b += 4) {
            s0 += p[(b + 0) * 256];
            s1 += p[(b + 1) * 256];
            s2 += p[(b + 2) * 256];
            s3 += p[(b + 3) * 256];
        }
        float s = (s0 + s1) + (s2 + s3);
        if (sel == 0) hsb[m] = s; else fcs[m] = s;
    }
    __syncthreads();
    if (tid < 384) {
        float s = b_iouh[tid];
        const f32x4* row = (const f32x4*)(W_iouh + tid * 128);
        #pragma unroll 8
        for (int m = 0; m < 32; ++m) {
            f32x4 w = row[m];
            s += w[0]*hsb[4*m] + w[1]*hsb[4*m+1] + w[2]*hsb[4*m+2] + w[3]*hsb[4*m+3];
        }
        iou[tid] = s;
    }
    __syncthreads();
    if (tid < 128) {
        float i = iou[tid], o = iou[128 + tid], u = iou[256 + tid];
        float cf = sig2(i * L2E) * (2.0f * sig2(u * 2.0f * L2E) - 1.0f) + fcs[tid];
        out[tid] = cf;
        hfin[tid] = sig2(o * L2E) * (2.0f * sig2(cf * 2.0f * L2E) - 1.0f);
    }
    __syncthreads();
    if (tid < 128) {
        float s = b_lout[tid];
        const f32x4* row = (const f32x4*)(W_lout + tid * 128);
        #pragma unroll 8
        for (int m = 0; m < 32; ++m) {
            f32x4 w = row[m];
            s += w[0]*hfin[4*m] + w[1]*hfin[4*m+1] + w[2]*hfin[4*m+2] + w[3]*hfin[4*m+3];
        }
        out[128 + tid] = s;
    }
}

extern "C" void kernel_launch(void* const* d_in, const int* in_sizes, int n_in,
                              void* d_out, int out_size, void* d_ws, size_t ws_size,
                              hipStream_t stream) {
    const float* numbers = (const float*)d_in[0];
    const float* w_num   = (const float*)d_in[1];
    const float* b_num   = (const float*)d_in[2];
    const float* W_ih    = (const float*)d_in[3];
    const float* W_hh    = (const float*)d_in[4];
    const float* b_ih    = (const float*)d_in[5];
    const float* b_hh    = (const float*)d_in[6];
    const float* W_fh    = (const float*)d_in[7];
    const float* b_fh    = (const float*)d_in[8];
    const float* W_iouh  = (const float*)d_in[9];
    const float* b_iouh  = (const float*)d_in[10];
    const float* W_lout  = (const float*)d_in[11];
    const float* b_lout  = (const float*)d_in[12];
    float* out = (float*)d_out;

    float* partials = (float*)d_ws;   // 256 blocks x 256 floats = 256 KB

    lstm_kernel<<<256, 1024, 0, stream>>>(numbers, w_num, b_num, W_ih, W_hh,
                                          b_ih, b_hh, W_fh, b_fh, partials);
    finalize_kernel<<<1, 384, 0, stream>>>(partials, W_iouh, b_iouh, W_lout, b_lout, out);
}

// Round 5
// 236.568 us; speedup vs baseline: 1.2612x; 1.1174x over previous
//
#include <hip/hip_runtime.h>
#include <math.h>

#define L2E  1.4426950408889634f
#define TL2E 2.8853900817779268f   // 2*log2(e)
#define HSTR 136   // h LDS row stride (bf16): 272B = 16*17, 16B-aligned per fragment

typedef __bf16 bf16x8 __attribute__((ext_vector_type(8)));
typedef float  f32x4  __attribute__((ext_vector_type(4)));

__device__ __forceinline__ float sig2(float y) {  // sigmoid(x), y = x*log2e
    return __builtin_amdgcn_rcpf(1.0f + __builtin_amdgcn_exp2f(-y));
}

// ================= single fused kernel =================
// 256 blocks x 512 thr (8 waves, 2/SIMD, 256-VGPR budget -> no spill).
// Wave w owns col-tile m0=w*16 for ALL 4 gates: 16 MFMA/step, tail 4 cells/lane,
// no redundancy, no exchange, one barrier/step.
// Epilogue: per-block partials -> last-arrival block does root Tree-LSTM + projection.
__global__ __launch_bounds__(512, 2) void lstm_kernel(
        const float* __restrict__ numbers,
        const float* __restrict__ w_num, const float* __restrict__ b_num,
        const float* __restrict__ W_ih,  const float* __restrict__ W_hh,
        const float* __restrict__ b_ih,  const float* __restrict__ b_hh,
        const float* __restrict__ W_fh,  const float* __restrict__ b_fh,
        const float* __restrict__ W_iouh, const float* __restrict__ b_iouh,
        const float* __restrict__ W_lout, const float* __restrict__ b_lout,
        float* __restrict__ partials, int* __restrict__ flag,
        float* __restrict__ out) {
    __shared__ unsigned short hbuf[2][16 * HSTR];
    __shared__ float xls[128 * 16];
    __shared__ float abw[1024];               // A[0..511], B[512..1023] (log2e-folded)
    __shared__ float wnb[256];                // w_num, b_num
    __shared__ float sx[100], lutm[100], luti[100];
    __shared__ float fin[768];                // hsb[0..127] fcs[128..255] iou[256..639] hfin[640..767]
    __shared__ float s_m99, s_i99;
    __shared__ int s_last;

    const int tid  = threadIdx.x;
    const int lane = tid & 63;
    const int wave = tid >> 6;        // 0..7
    const int quad = lane >> 4;
    const int lcol = lane & 15;
    const int m0   = wave * 16;
    const int r0   = blockIdx.x * 16;

    // ---- stage small vectors, zero h0 ----
    if (tid < 128) wnb[tid] = w_num[tid];
    else if (tid < 256) wnb[tid] = b_num[tid - 128];
    if (tid < 100) sx[tid] = numbers[tid];
    for (int i = tid; i < 16 * HSTR; i += 512) hbuf[0][i] = 0;
    __syncthreads();

    // stats over first 100 numbers (k=100 stats; used by all flats >= 100)
    if (wave == 0) {
        float v1 = sx[lane];
        float v2 = (lane < 36) ? sx[64 + lane] : 0.0f;
        float s = v1 + v2, ss = v1 * v1 + v2 * v2;
        #pragma unroll
        for (int off = 32; off >= 1; off >>= 1) {
            s += __shfl_xor(s, off);
            ss += __shfl_xor(ss, off);
        }
        if (lane == 0) {
            float mean = s * 0.01f;
            float var  = ss * 0.01f - mean * mean;
            if (var < 0.f) var = 0.f;
            float sd = sqrtf(var);
            s_m99 = mean;
            s_i99 = (sd > 1e-8f) ? (1.0f / sd) : 1.0f;
        }
    }
    if (blockIdx.x == 0 && tid < 100) {   // per-k LUT, only block 0's rows need it
        float s = 0.f, ss = 0.f;
        for (int j = 0; j <= tid; ++j) { float v = sx[j]; s += v; ss += v * v; }
        float cap  = (float)(tid + 1);
        float mean = s / cap;
        float var  = ss / cap - mean * mean;
        if (var < 0.f) var = 0.f;
        float sd = sqrtf(var);
        lutm[tid] = mean;
        luti[tid] = (cap > 3.0f && sd > 1e-8f) ? (1.0f / sd) : 1.0f;
    }
    // rank-1 input vectors: thread j dots W_ih[j][128:256] with w_num / b_num
    {
        int j = tid;
        const float* row = W_ih + j * 256 + 128;
        float a = 0.f, b = 0.f;
        #pragma unroll 4
        for (int m = 0; m < 128; m += 4) {
            f32x4 w  = *(const f32x4*)(row + m);
            f32x4 wn = *(const f32x4*)(wnb + m);
            f32x4 bn = *(const f32x4*)(wnb + 128 + m);
            a += w[0]*wn[0] + w[1]*wn[1] + w[2]*wn[2] + w[3]*wn[3];
            b += w[0]*bn[0] + w[1]*bn[1] + w[2]*bn[2] + w[3]*bn[3];
        }
        float sc = (j >= 256 && j < 384) ? TL2E : L2E;
        abw[j]       = a * sc;
        abw[512 + j] = (b + b_ih[j] + b_hh[j]) * sc;
    }
    __syncthreads();

    // normalize x into xls [t][row]
    for (int i = tid; i < 2048; i += 512) {
        int row = i >> 7, t = i & 127;
        int flat = (r0 + row) * 128 + t;
        float v = numbers[flat];
        float mn, iv;
        if (flat < 100) { mn = lutm[flat]; iv = luti[flat]; }
        else            { mn = s_m99;     iv = s_i99; }
        xls[t * 16 + row] = (v - mn) * iv;
    }

    // persistent W_hh B-fragments (bf16, log2e-folded): 64 VGPRs, fits 256-reg budget
    bf16x8 bfr[4][4];
    #pragma unroll
    for (int g = 0; g < 4; ++g) {
        float sc = (g == 2) ? TL2E : L2E;
        #pragma unroll
        for (int kk = 0; kk < 4; ++kk) {
            const float* p = W_hh + (g * 128 + m0 + lcol) * 128 + kk * 32 + quad * 8;
            f32x4 w0 = *(const f32x4*)p;
            f32x4 w1 = *(const f32x4*)(p + 4);
            bf16x8 bt;
            #pragma unroll
            for (int q = 0; q < 4; ++q) {
                bt[q]     = (__bf16)(w0[q] * sc);
                bt[q + 4] = (__bf16)(w1[q] * sc);
            }
            bfr[g][kk] = bt;
        }
    }
    float ag[4], bg[4];
    #pragma unroll
    for (int g = 0; g < 4; ++g) {
        ag[g] = abw[g * 128 + m0 + lcol];
        bg[g] = abw[512 + g * 128 + m0 + lcol];
    }
    float cst[4] = {0.f, 0.f, 0.f, 0.f};
    __syncthreads();

    // ---- main 128-step loop, unrolled by 2 (static LDS bases -> immediate offsets) ----
    auto step = [&](int t, const unsigned short* hinb, unsigned short* houtb) {
        const unsigned short* hp = hinb + lcol * HSTR + quad * 8;
        bf16x8 af[4];
        #pragma unroll
        for (int kk = 0; kk < 4; ++kk)
            af[kk] = *(const bf16x8*)(const void*)(hp + kk * 32);
        f32x4 xq = *(const f32x4*)(const void*)(xls + t * 16 + quad * 4);
        f32x4 aI, aF, aG, aO;
        #pragma unroll
        for (int r = 0; r < 4; ++r) {
            aI[r] = xq[r] * ag[0] + bg[0];
            aF[r] = xq[r] * ag[1] + bg[1];
            aG[r] = xq[r] * ag[2] + bg[2];
            aO[r] = xq[r] * ag[3] + bg[3];
        }
        #pragma unroll
        for (int kk = 0; kk < 4; ++kk) {
            aI = __builtin_amdgcn_mfma_f32_16x16x32_bf16(af[kk], bfr[0][kk], aI, 0, 0, 0);
            aF = __builtin_amdgcn_mfma_f32_16x16x32_bf16(af[kk], bfr[1][kk], aF, 0, 0, 0);
            aG = __builtin_amdgcn_mfma_f32_16x16x32_bf16(af[kk], bfr[2][kk], aG, 0, 0, 0);
            aO = __builtin_amdgcn_mfma_f32_16x16x32_bf16(af[kk], bfr[3][kk], aO, 0, 0, 0);
        }
        unsigned short* wp = houtb + quad * 4 * HSTR + m0 + lcol;
        #pragma unroll
        for (int r = 0; r < 4; ++r) {
            // 7 transcendentals: p & sig(f) share one rcp
            float e1 = __builtin_amdgcn_exp2f(-aI[r]);        // e^-i
            float e2 = __builtin_amdgcn_exp2f(aG[r]);         // e^2g
            float e5 = __builtin_amdgcn_exp2f(-aF[r]);        // e^-f
            float D1 = (1.0f + e1) * (e2 + 1.0f);
            float D2 = 1.0f + e5;
            float R  = __builtin_amdgcn_rcpf(D1 * D2);
            float c2 = (cst[r] * D1 + (e2 - 1.0f) * D2) * R;  // sig(f)c + sig(i)tanh(g)
            cst[r] = c2;
            float e3 = __builtin_amdgcn_exp2f(c2 * TL2E);     // e^2c
            float e4 = __builtin_amdgcn_exp2f(-aO[r]);        // e^-o
            float R2 = __builtin_amdgcn_rcpf((1.0f + e4) * (e3 + 1.0f));
            float h  = (e3 - 1.0f) * R2;                      // sig(o)tanh(c)
            wp[r * HSTR] = __builtin_bit_cast(unsigned short, (__bf16)h);
        }
        __syncthreads();
    };
    for (int t = 0; t < 128; t += 2) {
        step(t,     hbuf[0], hbuf[1]);
        step(t + 1, hbuf[1], hbuf[0]);
    }
    // final h (t=127) in hbuf[0]; final c in cst

    // ---- per-block partials: hs (sum of h over 16 rows), fc (sum sig(f_g)*c) ----
    {
        float hv = 0.f;
        #pragma unroll
        for (int r = 0; r < 4; ++r)
            hv += (float)__builtin_bit_cast(__bf16, hbuf[0][(quad * 4 + r) * HSTR + m0 + lcol]);
        hv += __shfl_xor(hv, 16);
        hv += __shfl_xor(hv, 32);
        if (lane < 16) partials[blockIdx.x * 256 + m0 + lane] = hv;
    }
    {
        f32x4 facc;
        float bb = b_fh[m0 + lcol] * L2E;
        #pragma unroll
        for (int r = 0; r < 4; ++r) facc[r] = bb;
        #pragma unroll
        for (int kk = 0; kk < 4; ++kk) {
            bf16x8 afr = *(const bf16x8*)(const void*)(hbuf[0] + lcol * HSTR + kk * 32 + quad * 8);
            const float* p = W_fh + (m0 + lcol) * 128 + kk * 32 + quad * 8;
            f32x4 w0 = *(const f32x4*)p;
            f32x4 w1 = *(const f32x4*)(p + 4);
            bf16x8 wt;
            #pragma unroll
            for (int q = 0; q < 4; ++q) {
                wt[q]     = (__bf16)(w0[q] * L2E);
                wt[q + 4] = (__bf16)(w1[q] * L2E);
            }
            facc = __builtin_amdgcn_mfma_f32_16x16x32_bf16(afr, wt, facc, 0, 0, 0);
        }
        float fcv = 0.f;
        #pragma unroll
        for (int r = 0; r < 4; ++r) fcv += sig2(facc[r]) * cst[r];
        fcv += __shfl_xor(fcv, 16);
        fcv += __shfl_xor(fcv, 32);
        if (lane < 16) partials[blockIdx.x * 256 + 128 + m0 + lane] = fcv;
    }

    // ---- last-arrival block performs the finalize (no spinning -> deadlock-free) ----
    __threadfence();
    __syncthreads();
    if (tid == 0) s_last = atomicAdd(flag, 1);
    __syncthreads();
    if (s_last != 255) return;
    __threadfence();

    // reduce partials (coalesced: threads 0..255 read slot j of block b)
    {
        int j = tid & 255;
        int half = tid >> 8;                  // 0/1: block halves
        const float* p = partials + half * 128 * 256 + j;
        float s0 = 0.f, s1 = 0.f, s2 = 0.f, s3 = 0.f;
        #pragma unroll 2
        for (int b = 0; b < 128; b += 4) {
            s0 += p[(b + 0) * 256];
            s1 += p[(b + 1) * 256];
            s2 += p[(b + 2) * 256];
            s3 += p[(b + 3) * 256];
        }
        float s = (s0 + s1) + (s2 + s3);
        if (half == 0) fin[j] = s;
        __syncthreads();
        if (half == 1) fin[j] += s;
    }
    __syncthreads();
    if (tid < 384) {   // iou = hs_bar @ W_iouh^T + b_iouh
        float s = b_iouh[tid];
        const f32x4* row = (const f32x4*)(W_iouh + tid * 128);
        #pragma unroll 8
        for (int m = 0; m < 32; ++m) {
            f32x4 w = row[m];
            s += w[0]*fin[4*m] + w[1]*fin[4*m+1] + w[2]*fin[4*m+2] + w[3]*fin[4*m+3];
        }
        fin[256 + tid] = s;
    }
    __syncthreads();
    if (tid < 128) {
        float i = fin[256 + tid], o = fin[384 + tid], u = fin[512 + tid];
        float cf = sig2(i * L2E) * (2.0f * sig2(u * TL2E) - 1.0f) + fin[128 + tid];
        out[tid] = cf;
        fin[640 + tid] = sig2(o * L2E) * (2.0f * sig2(cf * TL2E) - 1.0f);
    }
    __syncthreads();
    if (tid < 128) {
        float s = b_lout[tid];
        const f32x4* row = (const f32x4*)(W_lout + tid * 128);
        #pragma unroll 8
        for (int m = 0; m < 32; ++m) {
            f32x4 w = row[m];
            s += w[0]*fin[640+4*m] + w[1]*fin[641+4*m] + w[2]*fin[642+4*m] + w[3]*fin[643+4*m];
        }
        out[128 + tid] = s;
    }
}

extern "C" void kernel_launch(void* const* d_in, const int* in_sizes, int n_in,
                              void* d_out, int out_size, void* d_ws, size_t ws_size,
                              hipStream_t stream) {
    const float* numbers = (const float*)d_in[0];
    const float* w_num   = (const float*)d_in[1];
    const float* b_num   = (const float*)d_in[2];
    const float* W_ih    = (const float*)d_in[3];
    const float* W_hh    = (const float*)d_in[4];
    const float* b_ih    = (const float*)d_in[5];
    const float* b_hh    = (const float*)d_in[6];
    const float* W_fh    = (const float*)d_in[7];
    const float* b_fh    = (const float*)d_in[8];
    const float* W_iouh  = (const float*)d_in[9];
    const float* b_iouh  = (const float*)d_in[10];
    const float* W_lout  = (const float*)d_in[11];
    const float* b_lout  = (const float*)d_in[12];
    float* out = (float*)d_out;

    float* partials = (float*)d_ws;               // 256 blocks x 256 floats
    int*   flag     = (int*)((float*)d_ws + 256 * 256);

    hipMemsetAsync(flag, 0, sizeof(int), stream);
    lstm_kernel<<<256, 512, 0, stream>>>(numbers, w_num, b_num, W_ih, W_hh,
                                         b_ih, b_hh, W_fh, b_fh,
                                         W_iouh, b_iouh, W_lout, b_lout,
                                         partials, flag, out);
}